// Round 5
// baseline (246.064 us; speedup 1.0000x reference)
//
#include <hip/hip_runtime.h>

#define BB 16
#define CC 80
#define DD 1024
#define HW 196
#define NSP (BB * HW)        // 3136 = 49 full waves, zero lane waste
#define NCH 8                // d-chunks of 128
#define DCH 128
#define CPB 8                // classes per scores block
#define NCQ (CC / CPB)       // 10 class-groups
#define PCL 16               // classes per pool block
#define TWO_LOG2E 2.8853900817779268f

// ---------------- K1: scores ----------------
// Lane = flattened (b,hw). Block (g-tile, d-chunk 128, c-group 8).
// ALL 128 img values preload into VGPRs (loads issue as one batch -> VMEM
// latency overlaps the mul/scale and the first class's compute; compiler
// cannot "optimize away" the pipeline since iv[] is one live array).
// Then 8 classes * 128 sigmoids with word/fa on the scalar pipe (uniform
// addresses -> s_load). Stores x = -2*log2e * sum_d fa[d]/(e^{2 img w}+1);
// the affine remainder of the score cancels in softmax.
__global__ __launch_bounds__(256) void scores_k(const float* __restrict__ img,
                                                const float* __restrict__ word,
                                                const float* __restrict__ fa,
                                                float* __restrict__ partial) {
    const int g = blockIdx.x * 256 + threadIdx.x;   // flattened (b,hw)
    if (g >= NSP) return;                           // wave-uniform exit
    const int b  = g / HW;
    const int hw = g - b * HW;
    const int d0 = blockIdx.y * DCH;
    const int c0 = blockIdx.z * CPB;

    const float* ip = img + ((size_t)b * DD + d0) * HW + hw;

    // batch-issue all 128 strided (coalesced-across-lanes) loads
    float iv[DCH];
#pragma unroll
    for (int i = 0; i < DCH; ++i) iv[i] = ip[(size_t)i * HW];
    // pre-scale once: exp2(iv*w) == e^{2*img*word}
#pragma unroll
    for (int i = 0; i < DCH; ++i) iv[i] *= TWO_LOG2E;

    const float* fp = fa + d0;                      // uniform -> s_load
    const size_t pbase = (((size_t)b * NCH + blockIdx.y) * CC + c0) * HW + hw;

    for (int k = 0; k < CPB; ++k) {
        const float* wp = word + (size_t)(c0 + k) * DD + d0;  // uniform -> s_load
        float q0 = 0.f, q1 = 0.f, q2 = 0.f, q3 = 0.f;
        for (int i = 0; i < DCH; i += 4) {          // 32 iterations, 4-wide ILP
            float y0 = iv[i + 0] * wp[i + 0];
            float y1 = iv[i + 1] * wp[i + 1];
            float y2 = iv[i + 2] * wp[i + 2];
            float y3 = iv[i + 3] * wp[i + 3];
            float e0 = __builtin_amdgcn_exp2f(y0);
            float e1 = __builtin_amdgcn_exp2f(y1);
            float e2 = __builtin_amdgcn_exp2f(y2);
            float e3 = __builtin_amdgcn_exp2f(y3);
            float r0 = __builtin_amdgcn_rcpf(e0 + 1.f);
            float r1 = __builtin_amdgcn_rcpf(e1 + 1.f);
            float r2 = __builtin_amdgcn_rcpf(e2 + 1.f);
            float r3 = __builtin_amdgcn_rcpf(e3 + 1.f);
            q0 = fmaf(fp[i + 0], r0, q0);
            q1 = fmaf(fp[i + 1], r1, q1);
            q2 = fmaf(fp[i + 2], r2, q2);
            q3 = fmaf(fp[i + 3], r3, q3);
        }
        partial[pbase + (size_t)k * HW] = (-TWO_LOG2E) * ((q0 + q1) + (q2 + q3));
    }
}

// ---------------- K2: chunk-reduce + softmax over spatial positions ----------------
// partial already holds log2-scaled scores; just sum chunks, exp2, normalize.
__global__ __launch_bounds__(256) void softmax_k(const float* __restrict__ partial,
                                                 float* __restrict__ coef) {
    const int bc = blockIdx.x;
    const int b = bc / CC, c = bc - b * CC;
    const int t = threadIdx.x;

    float x = -3.4e38f;
    if (t < HW) {
        float P = 0.f;
#pragma unroll
        for (int ch = 0; ch < NCH; ++ch)
            P += partial[(((size_t)b * NCH + ch) * CC + c) * HW + t];
        x = P;
    }

    __shared__ float rmax[4], rsum[4];
    const int wv = t >> 6;

    float m = x;
#pragma unroll
    for (int off = 32; off >= 1; off >>= 1) m = fmaxf(m, __shfl_xor(m, off, 64));
    if ((t & 63) == 0) rmax[wv] = m;
    __syncthreads();
    m = fmaxf(fmaxf(rmax[0], rmax[1]), fmaxf(rmax[2], rmax[3]));

    float e = (t < HW) ? __builtin_amdgcn_exp2f(x - m) : 0.f;
    float s = e;
#pragma unroll
    for (int off = 32; off >= 1; off >>= 1) s += __shfl_xor(s, off, 64);
    if ((t & 63) == 0) rsum[wv] = s;
    __syncthreads();
    s = rsum[0] + rsum[1] + rsum[2] + rsum[3];

    if (t < HW) coef[((size_t)b * CC + c) * HW + t] = e * __builtin_amdgcn_rcpf(s);
}

// ---------------- K3: pooling out[b,c,d] = sum_hw coef[b,c,hw]*img[b,d,hw] ----
// Block (b, d-tile 64, c-group 16); 256 thr. img tile (50 KB) staged to LDS
// flat (dword row stride 196 == 4 mod 32 -> lane=d b128 reads spread all 32
// banks uniformly, 16B-aligned). Thread: d = t&63, class quad = t>>6.
// KEY FIX vs R3: the class-quad index goes through readfirstlane -> the coef
// pointer is provably wave-uniform -> coef float4 reads become s_load_dwordx4
// on the scalar pipe. Inner loop = 1 ds_read_b128 + 16 v_fma with SGPR
// operands (R3 issued 5 LDS b128 per step and was LDS-issue-bound).
__global__ __launch_bounds__(256) void pool_k(const float* __restrict__ img,
                                              const float* __restrict__ coef,
                                              float* __restrict__ out) {
    __shared__ float it[64 * HW];                 // 50176 B -> 3 blocks/CU
    const int b  = blockIdx.x;
    const int d0 = blockIdx.y * 64;
    const int cg = blockIdx.z * PCL;
    const int t  = threadIdx.x;

    const float4* src = (const float4*)(img + ((size_t)b * DD + d0) * HW);
    float4* dst = (float4*)it;
    for (int j = t; j < 64 * HW / 4; j += 256) dst[j] = src[j];
    __syncthreads();

    const int d   = t & 63;
    const int cq4 = __builtin_amdgcn_readfirstlane(t >> 6) * 4;   // uniform!
    const float* irow = it + d * HW;
    const float* cb = coef + ((size_t)b * CC + cg + cq4) * HW;    // uniform ptr

    float a0 = 0.f, a1 = 0.f, a2 = 0.f, a3 = 0.f;
    for (int h = 0; h < HW; h += 4) {
        float4 iv  = *(const float4*)(irow + h);                  // ds_read_b128
        float4 c0v = *(const float4*)(cb + h);                    // s_load_dwordx4
        float4 c1v = *(const float4*)(cb + HW + h);
        float4 c2v = *(const float4*)(cb + 2 * HW + h);
        float4 c3v = *(const float4*)(cb + 3 * HW + h);
        a0 = fmaf(iv.x, c0v.x, fmaf(iv.y, c0v.y, fmaf(iv.z, c0v.z, fmaf(iv.w, c0v.w, a0))));
        a1 = fmaf(iv.x, c1v.x, fmaf(iv.y, c1v.y, fmaf(iv.z, c1v.z, fmaf(iv.w, c1v.w, a1))));
        a2 = fmaf(iv.x, c2v.x, fmaf(iv.y, c2v.y, fmaf(iv.z, c2v.z, fmaf(iv.w, c2v.w, a2))));
        a3 = fmaf(iv.x, c3v.x, fmaf(iv.y, c3v.y, fmaf(iv.z, c3v.z, fmaf(iv.w, c3v.w, a3))));
    }

    float* op = out + ((size_t)b * CC + cg + cq4) * DD + d0 + d;
    op[0]      = a0;
    op[DD]     = a1;
    op[2 * DD] = a2;
    op[3 * DD] = a3;
}

extern "C" void kernel_launch(void* const* d_in, const int* in_sizes, int n_in,
                              void* d_out, int out_size, void* d_ws, size_t ws_size,
                              hipStream_t stream) {
    // inputs: [0]=batch_size(int,1) [1]=img [2]=word [3]=fc_a_w [4]=fc_a_b
    const float* img  = (const float*)d_in[1];
    const float* word = (const float*)d_in[2];
    const float* fa   = (const float*)d_in[3];
    float* out = (float*)d_out;

    // workspace (floats): partial[16][8][80][196] = 8.03MB | coef[16][80][196] = 2.51MB
    float* partial = (float*)d_ws;
    float* coef    = partial + (size_t)BB * NCH * CC * HW;

    scores_k<<<dim3((NSP + 255) / 256, NCH, NCQ), 256, 0, stream>>>(img, word, fa, partial);
    softmax_k<<<BB * CC, 256, 0, stream>>>(partial, coef);
    pool_k<<<dim3(BB, DD / 64, CC / PCL), 256, 0, stream>>>(img, coef, out);
}

// Round 6
// 181.593 us; speedup vs baseline: 1.3550x; 1.3550x over previous
//
#include <hip/hip_runtime.h>

#define BB 16
#define CC 80
#define DD 1024
#define HW 196
#define NSP (BB * HW)        // 3136 = 49 full waves, zero lane waste
#define NCH 8                // d-chunks of 128
#define DCH 128
#define CPB 4                // classes per scores block
#define NCQ (CC / CPB)       // 20 class-groups -> grid 2080 blocks
#define PCL 16               // classes per poolmax block
#define TWO_LOG2E 2.8853900817779268f

// ---------------- K1: scores (R3-proven structure, CPB=4) ----------------
// Lane = flattened (b,hw). Block (g-tile, d-chunk 128, c-group 4).
// img chunk loaded 32 regs at a time (compiler interleaves loads/compute;
// VGPR ~64 -> high occupancy). word/fa uniform -> scalar pipe.
// Stores x = -2*log2e * sum_d fa[d]/(e^{2 img w}+1); affine remainder of the
// true score cancels in softmax; exp2(x) == softmax numerator pre-max.
__global__ __launch_bounds__(256) void scores_k(const float* __restrict__ img,
                                                const float* __restrict__ word,
                                                const float* __restrict__ fa,
                                                float* __restrict__ partial) {
    const int g = blockIdx.x * 256 + threadIdx.x;
    if (g >= NSP) return;                           // wave-uniform exit
    const int b  = g / HW;
    const int hw = g - b * HW;
    const int d0 = blockIdx.y * DCH;
    const int c0 = blockIdx.z * CPB;

    const float* ip = img + ((size_t)b * DD + d0) * HW + hw;

    float p[CPB];
#pragma unroll
    for (int k = 0; k < CPB; ++k) p[k] = 0.f;

    for (int q = 0; q < DCH / 32; ++q) {            // 4 quarters of 32 d
        float iv[32];
        const float* qp = ip + (size_t)q * 32 * HW;
#pragma unroll
        for (int i = 0; i < 32; ++i)
            iv[i] = qp[(size_t)i * HW] * TWO_LOG2E;  // exp2(iv*w) == e^{2x}

        const float* fp = fa + d0 + q * 32;          // uniform -> SGPRs
#pragma unroll
        for (int k = 0; k < CPB; ++k) {
            const float* wp = word + (size_t)(c0 + k) * DD + d0 + q * 32;
            float p0 = 0.f, p1 = 0.f;
#pragma unroll
            for (int i = 0; i < 32; i += 2) {
                float y0 = iv[i]     * wp[i];
                float y1 = iv[i + 1] * wp[i + 1];
                float e0 = __builtin_amdgcn_exp2f(y0);
                float e1 = __builtin_amdgcn_exp2f(y1);
                float r0 = __builtin_amdgcn_rcpf(e0 + 1.f);
                float r1 = __builtin_amdgcn_rcpf(e1 + 1.f);
                p0 = fmaf(fp[i],     r0, p0);
                p1 = fmaf(fp[i + 1], r1, p1);
            }
            p[k] += p0 + p1;
        }
    }

#pragma unroll
    for (int k = 0; k < CPB; ++k)
        partial[(((size_t)b * NCH + blockIdx.y) * CC + (c0 + k)) * HW + hw]
            = (-TWO_LOG2E) * p[k];
}

// ---------------- K2: fused softmax + pooling ----------------
// Block (b, d-tile 64, c-group 16); 256 thr = 4 waves. LDS: img tile 50 KB +
// coef tile 12.5 KB = 62.7 KB (2 blocks/CU).
// Phase S: wave w computes softmax for classes cg+4w..cg+4w+3 from the
//   8-chunk partial sums (coalesced loads, 64-lane shuffle reduce, exp2),
//   writes coef rows to LDS. No global coef round-trip, no extra kernel.
// Phase P: d = t&63, wave's 4 classes: inner step = 1 lane-spread
//   ds_read_b128 (dword row stride 196 == 4 mod 32 -> all 32 banks, no
//   conflict) + 4 same-address b128 (broadcast, conflict-free) + 16 v_fma.
__global__ __launch_bounds__(256) void poolmax_k(const float* __restrict__ img,
                                                 const float* __restrict__ partial,
                                                 float* __restrict__ out) {
    __shared__ float it[64 * HW];                 // 50176 B
    __shared__ float ct[PCL * HW];                // 12544 B
    const int b  = blockIdx.x;
    const int d0 = blockIdx.y * 64;
    const int cg = blockIdx.z * PCL;
    const int t  = threadIdx.x;
    const int w  = t >> 6, l = t & 63;

    // stage img tile (flat contiguous float4 copy)
    const float4* src = (const float4*)(img + ((size_t)b * DD + d0) * HW);
    float4* dst = (float4*)it;
    for (int j = t; j < 64 * HW / 4; j += 256) dst[j] = src[j];

    // ---- Phase S: softmax for this wave's 4 classes ----
#pragma unroll
    for (int r = 4 * w; r < 4 * w + 4; ++r) {
        const int c = cg + r;
        float x0 = 0.f, x1 = 0.f, x2 = 0.f, x3 = 0.f;
#pragma unroll
        for (int ch = 0; ch < NCH; ++ch) {
            const float* pp = partial + (((size_t)b * NCH + ch) * CC + c) * HW;
            x0 += pp[l];
            x1 += pp[l + 64];
            x2 += pp[l + 128];
            if (l < HW - 192) x3 += pp[l + 192];
        }
        float x3m = (l < HW - 192) ? x3 : -3.4e38f;

        float m = fmaxf(fmaxf(x0, x1), fmaxf(x2, x3m));
#pragma unroll
        for (int off = 32; off >= 1; off >>= 1) m = fmaxf(m, __shfl_xor(m, off, 64));

        float e0 = __builtin_amdgcn_exp2f(x0 - m);
        float e1 = __builtin_amdgcn_exp2f(x1 - m);
        float e2 = __builtin_amdgcn_exp2f(x2 - m);
        float e3 = (l < HW - 192) ? __builtin_amdgcn_exp2f(x3 - m) : 0.f;

        float s = ((e0 + e1) + (e2 + e3));
#pragma unroll
        for (int off = 32; off >= 1; off >>= 1) s += __shfl_xor(s, off, 64);

        float inv = __builtin_amdgcn_rcpf(s);
        float* cr = ct + r * HW;
        cr[l]        = e0 * inv;
        cr[l + 64]   = e1 * inv;
        cr[l + 128]  = e2 * inv;
        if (l < HW - 192) cr[l + 192] = e3 * inv;
    }
    __syncthreads();

    // ---- Phase P: pooling ----
    const float* irow = it + l * HW;              // lane-spread, bank-perfect
    const float* crow = ct + (4 * w) * HW;        // wave-uniform broadcast

    float a0 = 0.f, a1 = 0.f, a2 = 0.f, a3 = 0.f;
    for (int h = 0; h < HW; h += 4) {
        float4 iv  = *(const float4*)(irow + h);
        float4 c0v = *(const float4*)(crow + h);
        float4 c1v = *(const float4*)(crow + HW + h);
        float4 c2v = *(const float4*)(crow + 2 * HW + h);
        float4 c3v = *(const float4*)(crow + 3 * HW + h);
        a0 = fmaf(iv.x, c0v.x, fmaf(iv.y, c0v.y, fmaf(iv.z, c0v.z, fmaf(iv.w, c0v.w, a0))));
        a1 = fmaf(iv.x, c1v.x, fmaf(iv.y, c1v.y, fmaf(iv.z, c1v.z, fmaf(iv.w, c1v.w, a1))));
        a2 = fmaf(iv.x, c2v.x, fmaf(iv.y, c2v.y, fmaf(iv.z, c2v.z, fmaf(iv.w, c2v.w, a2))));
        a3 = fmaf(iv.x, c3v.x, fmaf(iv.y, c3v.y, fmaf(iv.z, c3v.z, fmaf(iv.w, c3v.w, a3))));
    }

    float* op = out + ((size_t)b * CC + cg + 4 * w) * DD + d0 + l;
    op[0]          = a0;
    op[DD]         = a1;
    op[2 * (size_t)DD] = a2;
    op[3 * (size_t)DD] = a3;
}

extern "C" void kernel_launch(void* const* d_in, const int* in_sizes, int n_in,
                              void* d_out, int out_size, void* d_ws, size_t ws_size,
                              hipStream_t stream) {
    // inputs: [0]=batch_size(int,1) [1]=img [2]=word [3]=fc_a_w [4]=fc_a_b
    const float* img  = (const float*)d_in[1];
    const float* word = (const float*)d_in[2];
    const float* fa   = (const float*)d_in[3];
    float* out = (float*)d_out;

    // workspace (floats): partial[16][8][80][196] = 8.03 MB
    float* partial = (float*)d_ws;

    scores_k<<<dim3((NSP + 255) / 256, NCH, NCQ), 256, 0, stream>>>(img, word, fa, partial);
    poolmax_k<<<dim3(BB, DD / 64, CC / PCL), 256, 0, stream>>>(img, partial, out);
}

// Round 7
// 174.602 us; speedup vs baseline: 1.4093x; 1.0400x over previous
//
#include <hip/hip_runtime.h>

#define BB 16
#define CC 80
#define DD 1024
#define HW 196
#define NSP (BB * HW)        // 3136 = 49 full waves, zero lane waste
#define NCH 8                // d-chunks of 128
#define DCH 128
#define CPB 4                // classes per scores block
#define NCQ (CC / CPB)       // 20 class-groups -> grid 2080 blocks
#define PTC 16               // classes per pool block
#define TWO_LOG2E 2.8853900817779268f

// ---------------- K1: scores (R3/R5-proven structure) + imgT side-product ----
// Lane = flattened (b,hw). Block (g-tile, d-chunk 128, c-group 4).
// img chunk loaded 32 regs/quarter; word/fa uniform -> scalar pipe.
// blockIdx.z==0 blocks also dump their (already transposed-orientation) img
// registers to imgT[bhw][d] (32 f4 stores, uncoalesced but only 5% of blocks).
// Stores x = -2*log2e * sum_d fa[d]/(e^{2 img w}+1); the affine remainder of
// the true score cancels in softmax; exp2(x) == softmax numerator pre-max.
__global__ __launch_bounds__(256) void scores_k(const float* __restrict__ img,
                                                const float* __restrict__ word,
                                                const float* __restrict__ fa,
                                                float* __restrict__ partial,
                                                float* __restrict__ imgT) {
    const int g = blockIdx.x * 256 + threadIdx.x;
    if (g >= NSP) return;                           // wave-uniform exit
    const int b  = g / HW;
    const int hw = g - b * HW;
    const int d0 = blockIdx.y * DCH;
    const int c0 = blockIdx.z * CPB;

    const float* ip = img + ((size_t)b * DD + d0) * HW + hw;

    float p[CPB];
#pragma unroll
    for (int k = 0; k < CPB; ++k) p[k] = 0.f;

    for (int q = 0; q < DCH / 32; ++q) {            // 4 quarters of 32 d
        float iv[32];
        const float* qp = ip + (size_t)q * 32 * HW;
#pragma unroll
        for (int i = 0; i < 32; ++i)
            iv[i] = qp[(size_t)i * HW];

        if (blockIdx.z == 0) {                       // block-uniform branch
            float4* tp = (float4*)(imgT + (size_t)g * DD + d0 + q * 32);
#pragma unroll
            for (int i = 0; i < 8; ++i)
                tp[i] = make_float4(iv[4 * i], iv[4 * i + 1], iv[4 * i + 2], iv[4 * i + 3]);
        }

#pragma unroll
        for (int i = 0; i < 32; ++i)
            iv[i] *= TWO_LOG2E;                      // exp2(iv*w) == e^{2x}

        const float* fp = fa + d0 + q * 32;          // uniform -> SGPRs
#pragma unroll
        for (int k = 0; k < CPB; ++k) {
            const float* wp = word + (size_t)(c0 + k) * DD + d0 + q * 32;
            float p0 = 0.f, p1 = 0.f;
#pragma unroll
            for (int i = 0; i < 32; i += 2) {
                float y0 = iv[i]     * wp[i];
                float y1 = iv[i + 1] * wp[i + 1];
                float e0 = __builtin_amdgcn_exp2f(y0);
                float e1 = __builtin_amdgcn_exp2f(y1);
                float r0 = __builtin_amdgcn_rcpf(e0 + 1.f);
                float r1 = __builtin_amdgcn_rcpf(e1 + 1.f);
                p0 = fmaf(fp[i],     r0, p0);
                p1 = fmaf(fp[i + 1], r1, p1);
            }
            p[k] += p0 + p1;
        }
    }

#pragma unroll
    for (int k = 0; k < CPB; ++k)
        partial[(((size_t)b * NCH + blockIdx.y) * CC + (c0 + k)) * HW + hw]
            = (-TWO_LOG2E) * p[k];
}

// ---------------- K2: fused softmax + pooling via imgT ----------------
// Block (b, d-tile 256, c-group 16); 256 thr = 4 waves; LDS = 12.5 KB coef only.
// Phase S: wave w computes softmax for classes cg+4w..+3 from the 8-chunk
//   partials (coalesced loads, shuffle reduce, exp2) -> coef rows in LDS.
//   Redundancy only 4x (d-tiles), was 16x in R5.
// Phase P: lane l owns d-quad dt0+4l; per h-quad: 4 coalesced global float4
//   imgT loads + 4 broadcast ds_read_b128 (wave-uniform addr, conflict-free)
//   + 64 v_fma -> VALU-bound (LDS/FMA = 0.06 vs R5's 0.31).
__global__ __launch_bounds__(256) void poolT_k(const float* __restrict__ imgT,
                                               const float* __restrict__ partial,
                                               float* __restrict__ out) {
    __shared__ float ct[PTC * HW];                // 12544 B
    const int b   = blockIdx.x;
    const int dt0 = blockIdx.y * 256;
    const int cg  = blockIdx.z * PTC;
    const int t   = threadIdx.x;
    const int w   = t >> 6, l = t & 63;

    // ---- Phase S: softmax for this wave's 4 classes ----
#pragma unroll
    for (int rr = 0; rr < 4; ++rr) {
        const int r = 4 * w + rr;
        const int c = cg + r;
        float x0 = 0.f, x1 = 0.f, x2 = 0.f, x3 = 0.f;
#pragma unroll
        for (int ch = 0; ch < NCH; ++ch) {
            const float* pp = partial + (((size_t)b * NCH + ch) * CC + c) * HW;
            x0 += pp[l];
            x1 += pp[l + 64];
            x2 += pp[l + 128];
            if (l < HW - 192) x3 += pp[l + 192];
        }
        float x3m = (l < HW - 192) ? x3 : -3.4e38f;

        float m = fmaxf(fmaxf(x0, x1), fmaxf(x2, x3m));
#pragma unroll
        for (int off = 32; off >= 1; off >>= 1) m = fmaxf(m, __shfl_xor(m, off, 64));

        float e0 = __builtin_amdgcn_exp2f(x0 - m);
        float e1 = __builtin_amdgcn_exp2f(x1 - m);
        float e2 = __builtin_amdgcn_exp2f(x2 - m);
        float e3 = (l < HW - 192) ? __builtin_amdgcn_exp2f(x3 - m) : 0.f;

        float s = (e0 + e1) + (e2 + e3);
#pragma unroll
        for (int off = 32; off >= 1; off >>= 1) s += __shfl_xor(s, off, 64);

        float inv = __builtin_amdgcn_rcpf(s);
        float* cr = ct + r * HW;
        cr[l]       = e0 * inv;
        cr[l + 64]  = e1 * inv;
        cr[l + 128] = e2 * inv;
        if (l < HW - 192) cr[l + 192] = e3 * inv;
    }
    __syncthreads();

    // ---- Phase P: pooling, VALU-bound ----
    const float* crow = ct + (4 * w) * HW;        // wave-uniform -> broadcast
    const float* ib = imgT + ((size_t)b * HW) * DD + dt0 + 4 * l;

    float4 acc0 = {0,0,0,0}, acc1 = {0,0,0,0}, acc2 = {0,0,0,0}, acc3 = {0,0,0,0};
    for (int h = 0; h < HW; h += 4) {
        float4 i0 = *(const float4*)(ib + (size_t)(h    ) * DD);
        float4 i1 = *(const float4*)(ib + (size_t)(h + 1) * DD);
        float4 i2 = *(const float4*)(ib + (size_t)(h + 2) * DD);
        float4 i3 = *(const float4*)(ib + (size_t)(h + 3) * DD);
        float4 c0v = *(const float4*)(crow + h);
        float4 c1v = *(const float4*)(crow + HW + h);
        float4 c2v = *(const float4*)(crow + 2 * HW + h);
        float4 c3v = *(const float4*)(crow + 3 * HW + h);
#define ACC4(A, CV)                                                      \
        A.x = fmaf(CV.x, i0.x, fmaf(CV.y, i1.x, fmaf(CV.z, i2.x, fmaf(CV.w, i3.x, A.x)))); \
        A.y = fmaf(CV.x, i0.y, fmaf(CV.y, i1.y, fmaf(CV.z, i2.y, fmaf(CV.w, i3.y, A.y)))); \
        A.z = fmaf(CV.x, i0.z, fmaf(CV.y, i1.z, fmaf(CV.z, i2.z, fmaf(CV.w, i3.z, A.z)))); \
        A.w = fmaf(CV.x, i0.w, fmaf(CV.y, i1.w, fmaf(CV.z, i2.w, fmaf(CV.w, i3.w, A.w))));
        ACC4(acc0, c0v)
        ACC4(acc1, c1v)
        ACC4(acc2, c2v)
        ACC4(acc3, c3v)
#undef ACC4
    }

    float* ob = out + ((size_t)b * CC + cg + 4 * w) * DD + dt0 + 4 * l;
    *(float4*)(ob)              = acc0;
    *(float4*)(ob + DD)         = acc1;
    *(float4*)(ob + 2 * (size_t)DD) = acc2;
    *(float4*)(ob + 3 * (size_t)DD) = acc3;
}

extern "C" void kernel_launch(void* const* d_in, const int* in_sizes, int n_in,
                              void* d_out, int out_size, void* d_ws, size_t ws_size,
                              hipStream_t stream) {
    // inputs: [0]=batch_size(int,1) [1]=img [2]=word [3]=fc_a_w [4]=fc_a_b
    const float* img  = (const float*)d_in[1];
    const float* word = (const float*)d_in[2];
    const float* fa   = (const float*)d_in[3];
    float* out = (float*)d_out;

    // workspace (floats): partial[16][8][80][196] = 8.03 MB | imgT[3136][1024] = 12.85 MB
    float* partial = (float*)d_ws;
    float* imgT    = partial + (size_t)BB * NCH * CC * HW;

    scores_k<<<dim3((NSP + 255) / 256, NCH, NCQ), 256, 0, stream>>>(img, word, fa, partial, imgT);
    poolT_k<<<dim3(BB, DD / 256, CC / PTC), 256, 0, stream>>>(imgT, partial, out);
}

// Round 8
// 150.888 us; speedup vs baseline: 1.6308x; 1.1572x over previous
//
#include <hip/hip_runtime.h>

#define BB 16
#define CC 80
#define DD 1024
#define HW 196
#define NSP (BB * HW)        // 3136 = 49 full waves, zero lane waste
#define NCH 8                // d-chunks of 128
#define DCH 128
#define CPB 4                // classes per scores block
#define NCQ (CC / CPB)       // 20 class-groups -> grid 2080 blocks
#define TWO_LOG2E 2.8853900817779268f

// ---------------- K1: scores (R3/R5-proven structure) + imgT side-product ----
// Lane = flattened (b,hw). Block (g-tile, d-chunk 128, c-group 4).
// img chunk loaded 32 regs/quarter; word/fa uniform -> scalar pipe.
// blockIdx.z==0 blocks also dump their (already transposed-orientation) img
// registers to imgT[bhw][d] (32 f4 stores, only 5% of blocks).
// Stores x = -2*log2e * sum_d fa[d]/(e^{2 img w}+1); the affine remainder of
// the true score cancels in softmax; exp2(x) == softmax numerator pre-max.
__global__ __launch_bounds__(256) void scores_k(const float* __restrict__ img,
                                                const float* __restrict__ word,
                                                const float* __restrict__ fa,
                                                float* __restrict__ partial,
                                                float* __restrict__ imgT) {
    const int g = blockIdx.x * 256 + threadIdx.x;
    if (g >= NSP) return;                           // wave-uniform exit
    const int b  = g / HW;
    const int hw = g - b * HW;
    const int d0 = blockIdx.y * DCH;
    const int c0 = blockIdx.z * CPB;

    const float* ip = img + ((size_t)b * DD + d0) * HW + hw;

    float p[CPB];
#pragma unroll
    for (int k = 0; k < CPB; ++k) p[k] = 0.f;

    for (int q = 0; q < DCH / 32; ++q) {            // 4 quarters of 32 d
        float iv[32];
        const float* qp = ip + (size_t)q * 32 * HW;
#pragma unroll
        for (int i = 0; i < 32; ++i)
            iv[i] = qp[(size_t)i * HW];

        if (blockIdx.z == 0) {                       // block-uniform branch
            float4* tp = (float4*)(imgT + (size_t)g * DD + d0 + q * 32);
#pragma unroll
            for (int i = 0; i < 8; ++i)
                tp[i] = make_float4(iv[4 * i], iv[4 * i + 1], iv[4 * i + 2], iv[4 * i + 3]);
        }

#pragma unroll
        for (int i = 0; i < 32; ++i)
            iv[i] *= TWO_LOG2E;                      // exp2(iv*w) == e^{2x}

        const float* fp = fa + d0 + q * 32;          // uniform -> SGPRs
#pragma unroll
        for (int k = 0; k < CPB; ++k) {
            const float* wp = word + (size_t)(c0 + k) * DD + d0 + q * 32;
            float p0 = 0.f, p1 = 0.f;
#pragma unroll
            for (int i = 0; i < 32; i += 2) {
                float y0 = iv[i]     * wp[i];
                float y1 = iv[i + 1] * wp[i + 1];
                float e0 = __builtin_amdgcn_exp2f(y0);
                float e1 = __builtin_amdgcn_exp2f(y1);
                float r0 = __builtin_amdgcn_rcpf(e0 + 1.f);
                float r1 = __builtin_amdgcn_rcpf(e1 + 1.f);
                p0 = fmaf(fp[i],     r0, p0);
                p1 = fmaf(fp[i + 1], r1, p1);
            }
            p[k] += p0 + p1;
        }
    }

#pragma unroll
    for (int k = 0; k < CPB; ++k)
        partial[(((size_t)b * NCH + blockIdx.y) * CC + (c0 + k)) * HW + hw]
            = (-TWO_LOG2E) * p[k];
}

// ---------------- K2: fused softmax + pooling, HIGH OCCUPANCY ----------------
// Grid (16 b, 4 d-tiles of 256, 20 c-groups of 4) = 1280 blocks x 4 waves
// = 20 waves/CU = 5 waves/SIMD (R6 had 1.25 -- latency-crippled).
// Phase S: wave w computes the softmax for class cg+w from the 8-chunk
//   partials (coalesced loads, 64-lane shuffle reduce, exp2) -> 3.1 KB LDS.
// Phase P: thread owns d = dt0 + t. Per 4-h step: 4 coalesced global b32
//   imgT loads + 4 broadcast ds_read_b128 (same-address -> conflict-free)
//   + 16 v_fma. All three pipes ~5-8 us/CU and overlap at 5 waves/SIMD.
__global__ __launch_bounds__(256) void pool2_k(const float* __restrict__ imgT,
                                               const float* __restrict__ partial,
                                               float* __restrict__ out) {
    __shared__ float ct[4 * HW];                  // 3136 B
    const int b   = blockIdx.x;
    const int dt0 = blockIdx.y * 256;
    const int cg  = blockIdx.z * 4;
    const int t   = threadIdx.x;
    const int w   = t >> 6, l = t & 63;

    // ---- Phase S: wave w -> softmax of class cg+w ----
    {
        const int c = cg + w;
        float x0 = 0.f, x1 = 0.f, x2 = 0.f, x3 = 0.f;
#pragma unroll
        for (int ch = 0; ch < NCH; ++ch) {
            const float* pp = partial + (((size_t)b * NCH + ch) * CC + c) * HW;
            x0 += pp[l];
            x1 += pp[l + 64];
            x2 += pp[l + 128];
            if (l < HW - 192) x3 += pp[l + 192];
        }
        float x3m = (l < HW - 192) ? x3 : -3.4e38f;

        float m = fmaxf(fmaxf(x0, x1), fmaxf(x2, x3m));
#pragma unroll
        for (int off = 32; off >= 1; off >>= 1) m = fmaxf(m, __shfl_xor(m, off, 64));

        float e0 = __builtin_amdgcn_exp2f(x0 - m);
        float e1 = __builtin_amdgcn_exp2f(x1 - m);
        float e2 = __builtin_amdgcn_exp2f(x2 - m);
        float e3 = (l < HW - 192) ? __builtin_amdgcn_exp2f(x3 - m) : 0.f;

        float s = (e0 + e1) + (e2 + e3);
#pragma unroll
        for (int off = 32; off >= 1; off >>= 1) s += __shfl_xor(s, off, 64);

        float inv = __builtin_amdgcn_rcpf(s);
        float* cr = ct + w * HW;
        cr[l]       = e0 * inv;
        cr[l + 64]  = e1 * inv;
        cr[l + 128] = e2 * inv;
        if (l < HW - 192) cr[l + 192] = e3 * inv;
    }
    __syncthreads();

    // ---- Phase P: pooling, d = dt0 + t ----
    const float* ib = imgT + (size_t)b * HW * DD + dt0 + t;

    float a0 = 0.f, a1 = 0.f, a2 = 0.f, a3 = 0.f;
#pragma unroll 7
    for (int h = 0; h < HW; h += 4) {
        float i0 = ib[(size_t)(h    ) * DD];
        float i1 = ib[(size_t)(h + 1) * DD];
        float i2 = ib[(size_t)(h + 2) * DD];
        float i3 = ib[(size_t)(h + 3) * DD];
        float4 c0v = *(const float4*)(ct + h);            // broadcast b128
        float4 c1v = *(const float4*)(ct + HW + h);
        float4 c2v = *(const float4*)(ct + 2 * HW + h);
        float4 c3v = *(const float4*)(ct + 3 * HW + h);
        a0 = fmaf(c0v.x, i0, fmaf(c0v.y, i1, fmaf(c0v.z, i2, fmaf(c0v.w, i3, a0))));
        a1 = fmaf(c1v.x, i0, fmaf(c1v.y, i1, fmaf(c1v.z, i2, fmaf(c1v.w, i3, a1))));
        a2 = fmaf(c2v.x, i0, fmaf(c2v.y, i1, fmaf(c2v.z, i2, fmaf(c2v.w, i3, a2))));
        a3 = fmaf(c3v.x, i0, fmaf(c3v.y, i1, fmaf(c3v.z, i2, fmaf(c3v.w, i3, a3))));
    }

    float* ob = out + ((size_t)b * CC + cg) * DD + dt0 + t;
    ob[0]              = a0;
    ob[DD]             = a1;
    ob[2 * (size_t)DD] = a2;
    ob[3 * (size_t)DD] = a3;
}

extern "C" void kernel_launch(void* const* d_in, const int* in_sizes, int n_in,
                              void* d_out, int out_size, void* d_ws, size_t ws_size,
                              hipStream_t stream) {
    // inputs: [0]=batch_size(int,1) [1]=img [2]=word [3]=fc_a_w [4]=fc_a_b
    const float* img  = (const float*)d_in[1];
    const float* word = (const float*)d_in[2];
    const float* fa   = (const float*)d_in[3];
    float* out = (float*)d_out;

    // workspace (floats): partial[16][8][80][196] = 8.03 MB | imgT[3136][1024] = 12.85 MB
    float* partial = (float*)d_ws;
    float* imgT    = partial + (size_t)BB * NCH * CC * HW;

    scores_k<<<dim3((NSP + 255) / 256, NCH, NCQ), 256, 0, stream>>>(img, word, fa, partial, imgT);
    pool2_k<<<dim3(BB, DD / 256, CC / 4), 256, 0, stream>>>(imgT, partial, out);
}